// Round 18
// baseline (147.723 us; speedup 1.0000x reference)
//
#include <hip/hip_runtime.h>
#include <hip/hip_bf16.h>
#include <stdint.h>

// Problem constants
constexpr int NB = 8;     // batch
constexpr int NS = 1024;  // seq
constexpr int ND = 1024;  // model dim
constexpr int NH = 16;    // heads
constexpr int NDK = 64;   // head dim
constexpr int NKT = ND / 64;  // 16 K-tiles per GEMM

typedef __bf16 bf16_t;
typedef __attribute__((ext_vector_type(8))) __bf16 bf16x8;
typedef __attribute__((ext_vector_type(4))) __bf16 bf16x4;
typedef __attribute__((ext_vector_type(4))) float f32x4;
typedef __attribute__((ext_vector_type(16))) float f32x16;

#define GLL16(g, s) __builtin_amdgcn_global_load_lds( \
    (const __attribute__((address_space(1))) void*)(g), \
    (__attribute__((address_space(3))) void*)(s), 16, 0, 0)

__device__ __forceinline__ unsigned cvtpk_bf16(float lo, float hi) {
  unsigned r;
  asm("v_cvt_pk_bf16_f32 %0, %1, %2" : "=v"(r) : "v"(lo), "v"(hi));
  return r;
}

// ---------------- fp32 -> bf16 convert (weights only) ----------------
__device__ __forceinline__ void cvt_body(const float* __restrict__ s,
                                         bf16_t* __restrict__ d, long n) {
  long i0 = (long)(blockIdx.x * blockDim.x + threadIdx.x) * 4;
  long step = (long)gridDim.x * blockDim.x * 4;
  for (long i = i0; i < n; i += step) {
    float4 f = *(const float4*)(s + i);
    bf16x4 o;
    o[0] = (bf16_t)f.x; o[1] = (bf16_t)f.y; o[2] = (bf16_t)f.z; o[3] = (bf16_t)f.w;
    *(bf16x4*)(d + i) = o;
  }
}

__global__ __launch_bounds__(256) void cvt4_kernel(const float* s0, bf16_t* d0,
                                                   const float* s1, bf16_t* d1,
                                                   const float* s2, bf16_t* d2,
                                                   const float* s3, bf16_t* d3, long n) {
  const float* s = blockIdx.y == 0 ? s0 : blockIdx.y == 1 ? s1 : blockIdx.y == 2 ? s2 : s3;
  bf16_t* d = blockIdx.y == 0 ? d0 : blockIdx.y == 1 ? d1 : blockIdx.y == 2 ? d2 : d3;
  cvt_body(s, d, n);
}

// ---------------- QKV GEMM, fused fp32->bf16 A-convert, 128x128 tile -----
// EXACT R16 structure (proven best): 256 threads, 4 waves (2M x 2N), BK=64,
// 2 blocks/CU (80KB LDS). A: reg-staged fp32 distance-2 (faA/faB parity);
// B: GLL16 XOR-swizzled, 3 bufs. Ledger: prologue [A0:8,A1:8,B0:4,B1:4] ->
// vmcnt(4) keeps B1; body(t) issues A(t+2):8 then B(t+2):4, computes,
// vmcnt(12) retires A(t+1)+B(t+1) (never 0 mid-loop), writeA(t+1),
// lgkm(0)+barrier. z==2 (V) writes output transposed per head.
__global__ __launch_bounds__(256, 2) void gemm_qkv(
    const float* A0, const bf16_t* W0, const float* b0, bf16_t* C0,
    const float* A1, const bf16_t* W1, const float* b1, bf16_t* C1,
    const float* A2, const bf16_t* W2, const float* b2, bf16_t* C2) {
  __shared__ bf16_t S[5 * 8192];  // A 2x8192 + B 3x8192 elems (80KB)
  const int o = blockIdx.x;
  const int xcd = o & 7, s = o >> 3;   // s in [0,192)
  const int bx = s & 7, u = s >> 3;    // u in [0,24)
  const int zby = xcd + 8 * u;         // 0..191
  const int z = zby >> 6, by = zby & 63;
  const float* A = z == 0 ? A0 : z == 1 ? A1 : A2;
  const bf16_t* W = z == 0 ? W0 : z == 1 ? W1 : W2;
  const float* bb = z == 0 ? b0 : z == 1 ? b1 : b2;
  bf16_t* C = z == 0 ? C0 : z == 1 ? C1 : C2;

  const int tid = threadIdx.x;           // 0..255
  const int l = tid & 63, w = tid >> 6;  // 4 waves
  const int wr = w >> 1, wc = w & 1;     // 2M x 2N
  const int g = l >> 4, r = l & 15;
  const int m0 = by * 128, n0 = bx * 128;
  const int wbase = w * 512;

  bf16_t* Ab = S;            // 2 x 8192 elems
  bf16_t* Bb = S + 16384;    // 3 x 8192 elems

  float4 faA[8], faB[8];
  auto issueA = [&](int t, float4 (&dst)[8]) {
#pragma unroll
    for (int it = 0; it < 4; ++it) {
      const float* p = A + (size_t)(m0 + it * 32 + (tid >> 3)) * ND + t * 64 + (tid & 7) * 8;
      dst[it * 2]     = *(const float4*)p;
      dst[it * 2 + 1] = *(const float4*)(p + 4);
    }
  };
  auto writeA = [&](int ab, float4 (&src)[8]) {
#pragma unroll
    for (int it = 0; it < 4; ++it) {
      int row = it * 32 + (tid >> 3), c = tid & 7;
      bf16x8 ov;
      ov[0] = (bf16_t)src[it * 2].x;     ov[1] = (bf16_t)src[it * 2].y;
      ov[2] = (bf16_t)src[it * 2].z;     ov[3] = (bf16_t)src[it * 2].w;
      ov[4] = (bf16_t)src[it * 2 + 1].x; ov[5] = (bf16_t)src[it * 2 + 1].y;
      ov[6] = (bf16_t)src[it * 2 + 1].z; ov[7] = (bf16_t)src[it * 2 + 1].w;
      *(bf16x8*)(Ab + ab * 8192 + row * 64 + ((c ^ (row & 7)) << 3)) = ov;
    }
  };
  auto stageB = [&](int qb, int t) {
#pragma unroll
    for (int it = 0; it < 4; ++it) {
      int idx = it * 256 + tid;
      int row = idx >> 3, c = (idx & 7) ^ (row & 7);
      GLL16(W + (size_t)(n0 + row) * ND + (t << 6) + c * 8,
            Bb + qb * 8192 + it * 2048 + wbase);
    }
  };

  f32x4 acc[4][4] = {};

  // prologue: queue [A0:8, A1:8, B0:4, B1:4]; vmcnt(4) keeps only B1.
  issueA(0, faA);
  issueA(1, faB);
  stageB(0, 0);
  stageB(1, 1);
  asm volatile("s_waitcnt vmcnt(4)" ::: "memory");
  __builtin_amdgcn_sched_barrier(0);
  writeA(0, faA);
  asm volatile("s_waitcnt lgkmcnt(0)" ::: "memory");
  __builtin_amdgcn_s_barrier();

  auto bodyT = [&](int t, float4 (&fiss)[8], float4 (&fwr)[8]) {
    if (t + 2 < NKT) issueA(t + 2, fiss);
    __builtin_amdgcn_sched_barrier(0);   // pin: A issues before B issues
    if (t + 2 < NKT) stageB((t + 2) % 3, t + 2);
    __builtin_amdgcn_sched_barrier(0);   // pin: issues before compute

    const bf16_t* a_ = Ab + (t & 1) * 8192;
    const bf16_t* b_ = Bb + (t % 3) * 8192;
#pragma unroll
    for (int kk = 0; kk < 2; ++kk) {
      bf16x8 af[4], bw[4];
#pragma unroll
      for (int m = 0; m < 4; ++m) {
        int row = wr * 64 + m * 16 + r;
        af[m] = *(const bf16x8*)(a_ + row * 64 + (((kk * 4 + g) ^ (row & 7)) << 3));
      }
#pragma unroll
      for (int n = 0; n < 4; ++n) {
        int row = wc * 64 + n * 16 + r;
        bw[n] = *(const bf16x8*)(b_ + row * 64 + (((kk * 4 + g) ^ (row & 7)) << 3));
      }
      __builtin_amdgcn_s_setprio(1);
#pragma unroll
      for (int m = 0; m < 4; ++m)
#pragma unroll
        for (int n = 0; n < 4; ++n)
          acc[m][n] = __builtin_amdgcn_mfma_f32_16x16x32_bf16(af[m], bw[n], acc[m][n], 0, 0, 0);
      __builtin_amdgcn_s_setprio(0);
    }

    // retire A(t+1):8 + B(t+1):4; keep A(t+2):8 + B(t+2):4 in flight
    if (t + 2 < NKT)      asm volatile("s_waitcnt vmcnt(12)" ::: "memory");
    else                  asm volatile("s_waitcnt vmcnt(0)" ::: "memory");
    __builtin_amdgcn_sched_barrier(0);   // rule 18: fwr regs read below
    if (t + 1 < NKT) writeA((t + 1) & 1, fwr);
    asm volatile("s_waitcnt lgkmcnt(0)" ::: "memory");
    __builtin_amdgcn_s_barrier();        // publish tile t+1
  };

#pragma unroll 1
  for (int tt = 0; tt < NKT; tt += 2) {  // parity-unrolled: static fa buffers
    bodyT(tt, faA, faB);
    bodyT(tt + 1, faB, faA);
  }

  if (z == 2) {
    // transposed per-head epilogue: v1t[((b*16+h)*64+dk)*1024 + s]
#pragma unroll
    for (int n = 0; n < 4; ++n) {
      int col = n0 + wc * 64 + n * 16 + r;
      int hh = col >> 6, dk = col & 63;
      float bv = bb[col];
#pragma unroll
      for (int m = 0; m < 4; ++m) {
        int row0 = m0 + wr * 64 + m * 16 + g * 4;
        int b_ = row0 >> 10, s0 = row0 & 1023;
        bf16x4 o4;
#pragma unroll
        for (int j = 0; j < 4; ++j) o4[j] = (bf16_t)(acc[m][n][j] + bv);
        *(bf16x4*)(C + (((size_t)b_ * 16 + hh) * 64 + dk) * 1024 + s0) = o4;
      }
    }
  } else {
#pragma unroll
    for (int n = 0; n < 4; ++n) {
      int col = n0 + wc * 64 + n * 16 + r;
      float bv = bb[col];
#pragma unroll
      for (int m = 0; m < 4; ++m) {
        int row0 = m0 + wr * 64 + m * 16 + g * 4;
#pragma unroll
        for (int j = 0; j < 4; ++j)
          C[(size_t)(row0 + j) * ND + col] = (bf16_t)(acc[m][n][j] + bv);
      }
    }
  }
}

// ---------------- O-projection GEMM (unchanged R8 structure) ----------------
__global__ __launch_bounds__(512, 2) void gemm_bt(const bf16_t* __restrict__ A,
                                                  const bf16_t* __restrict__ W,
                                                  const float* __restrict__ bias,
                                                  float* __restrict__ Cout,
                                                  int M, int N, int K) {
  __shared__ bf16_t S[3 * 24576];
  const int o = blockIdx.x;
  const int xcd = o & 7, s = o >> 3;   // s in [0,32)
  const int bx = s & 7, u = s >> 3;    // u in [0,4)
  const int by = xcd + 8 * u;

  const int tid = threadIdx.x;
  const int l = tid & 63, w = tid >> 6;
  const int wr = w >> 1, wc = w & 1;
  const int g = l >> 4, r = l & 15;
  const int m0 = by * 256, n0 = bx * 128;
  const int wbase = w * 512;

  auto stageA2 = [&](int q, int t, int half) {
#pragma unroll
    for (int it = half * 2; it < half * 2 + 2; ++it) {
      int idx = it * 512 + tid;
      int row = idx >> 3, c = (idx & 7) ^ (row & 7);
      GLL16(A + (size_t)(m0 + row) * K + (t << 6) + c * 8,
            S + q * 24576 + it * 4096 + wbase);
    }
  };
  auto stageB2 = [&](int q, int t) {
#pragma unroll
    for (int it = 0; it < 2; ++it) {
      int idx = it * 512 + tid;
      int row = idx >> 3, c = (idx & 7) ^ (row & 7);
      GLL16(W + (size_t)(n0 + row) * K + (t << 6) + c * 8,
            S + q * 24576 + 16384 + it * 4096 + wbase);
    }
  };

  f32x4 acc[4][4] = {};
  const int NKT2 = K >> 6;

  stageA2(0, 0, 0); stageA2(0, 0, 1); stageB2(0, 0);
  stageA2(1, 1, 0); stageA2(1, 1, 1); stageB2(1, 1);

  int q = 0;
  for (int t = 0; t < NKT2; ++t) {
    const bool pf = (t + 2 < NKT2);
    int q2 = q + 2; if (q2 >= 3) q2 -= 3;

    if (t + 1 < NKT2) asm volatile("s_waitcnt vmcnt(6)" ::: "memory");
    else              asm volatile("s_waitcnt vmcnt(0)" ::: "memory");
    __builtin_amdgcn_s_barrier();

    const bf16_t* a_ = S + q * 24576;
    const bf16_t* b_ = a_ + 16384;

#pragma unroll
    for (int kk = 0; kk < 2; ++kk) {
      bf16x8 bw[4];
#pragma unroll
      for (int n = 0; n < 4; ++n) {
        int row = wc * 64 + n * 16 + r;
        bw[n] = *(const bf16x8*)(b_ + row * 64 + (((kk * 4 + g) ^ (row & 7)) << 3));
      }
#pragma unroll
      for (int mh = 0; mh < 2; ++mh) {
        bf16x8 af[2];
#pragma unroll
        for (int i = 0; i < 2; ++i) {
          int row = wr * 64 + (mh * 2 + i) * 16 + r;
          af[i] = *(const bf16x8*)(a_ + row * 64 + (((kk * 4 + g) ^ (row & 7)) << 3));
        }
        if (pf) {
          int ph = kk * 2 + mh;
          if (ph == 0)      stageA2(q2, t + 2, 0);
          else if (ph == 1) stageA2(q2, t + 2, 1);
          else if (ph == 2) stageB2(q2, t + 2);
        }
        __builtin_amdgcn_s_barrier();
        asm volatile("s_waitcnt lgkmcnt(0)" ::: "memory");
        __builtin_amdgcn_sched_barrier(0);
        __builtin_amdgcn_s_setprio(1);
#pragma unroll
        for (int i = 0; i < 2; ++i)
#pragma unroll
          for (int n = 0; n < 4; ++n)
            acc[mh * 2 + i][n] = __builtin_amdgcn_mfma_f32_16x16x32_bf16(
                af[i], bw[n], acc[mh * 2 + i][n], 0, 0, 0);
        __builtin_amdgcn_s_setprio(0);
        __builtin_amdgcn_sched_barrier(0);
      }
    }
    ++q; if (q >= 3) q -= 3;
  }

#pragma unroll
  for (int n = 0; n < 4; ++n) {
    int col = n0 + wc * 64 + n * 16 + r;
    float bv = bias[col];
#pragma unroll
    for (int m = 0; m < 4; ++m) {
      int row0 = m0 + wr * 64 + m * 16 + g * 4;
#pragma unroll
      for (int j = 0; j < 4; ++j)
        Cout[(size_t)(row0 + j) * N + col] = acc[m][n][j] + bv;
    }
  }
}

// ---------------- causal flash attention (32x32, 1 q-tile/block) ----------
// R18 change: drop the q-tile pairing -> 1024 blocks (one 128-row q-tile
// each), 4 blocks/CU co-resident (16 waves/CU) so cross-block slip hides
// the per-iteration overhead (the R16-proven mechanism). Causal imbalance
// balanced by alternating qt map (idx even -> 7-idx/2, odd -> idx/2): on
// each XCD blocks arrive long/short interleaved. Inner loop = R14 exact.
__global__ __launch_bounds__(256, 4) void attn_kernel(const bf16_t* __restrict__ Q1,
                                                      const bf16_t* __restrict__ K1,
                                                      const bf16_t* __restrict__ V1t,
                                                      bf16_t* __restrict__ attn) {
  __shared__ bf16_t Kt[2][64 * 64];
  __shared__ bf16_t Vt[2][64 * 64];

  const int tid = threadIdx.x;           // 0..255
  const int l = tid & 63, w = tid >> 6;  // 4 waves
  const int q32 = l & 31, h5 = l >> 5;

  // XCD swizzle (1024 blocks): os = (o&7)*128 + (o>>3); idx -> qt alternates
  // long/short so co-resident blocks balance.
  const int o = blockIdx.x;
  const int os = (o & 7) * 128 + (o >> 3);
  const int idx = os & 7, hb = os >> 3;
  const int qt = (idx & 1) ? (idx >> 1) : (7 - (idx >> 1));
  const int h = hb & 15, b = hb >> 4;

  constexpr float SC = 0.18033688011112042f;  // 0.125 * log2(e)
  const bf16_t* vbase = V1t + ((size_t)(b * 16 + h) * 64) * 1024;

  auto stageKV = [&](int kt2, int pb) {
    const int k0 = kt2 * 64;
#pragma unroll
    for (int it = 0; it < 2; ++it) {
      int idx2 = it * 256 + tid;
      int row = idx2 >> 3, c = (idx2 & 7) ^ (row & 7);
      GLL16(K1 + ((size_t)b * NS + k0 + row) * ND + h * 64 + c * 8,
            &Kt[pb][it * 2048 + w * 512]);
      GLL16(vbase + (size_t)row * 1024 + k0 + c * 8,
            &Vt[pb][it * 2048 + w * 512]);
    }
  };

  const int qrow_g = qt * 128 + w * 32 + q32;   // this lane's q-row

  const bf16_t* qptr = Q1 + ((size_t)b * NS + qrow_g) * ND + h * 64;
  bf16x8 qf[4];
#pragma unroll
  for (int ds = 0; ds < 4; ++ds) {
    qf[ds] = *(const bf16x8*)(qptr + ds * 16 + h5 * 8);
#pragma unroll
    for (int i = 0; i < 8; ++i) qf[ds][i] = (bf16_t)((float)qf[ds][i] * SC);
  }

  float mrun = -1e30f, lrun = 0.f;
  f32x16 oacc0 = {}, oacc1 = {};

  const int nkt = 2 * qt + 2;
  stageKV(0, 0);    // prologue

  for (int kt = 0; kt < nkt; ++kt) {
    const int p = kt & 1;
    const int k0 = kt * 64;

    __syncthreads();  // drains GLLs for tile kt (covered by prev compute)

    if (kt + 1 < nkt) stageKV(kt + 1, p ^ 1);

    // --- QK^T: s0 = keys k0..k0+31, s1 = keys k0+32..k0+63 (rows), col=q
    f32x16 s0 = {}, s1 = {};
    __builtin_amdgcn_s_setprio(1);
#pragma unroll
    for (int ds = 0; ds < 4; ++ds) {
      int dk2b = (ds * 16 + h5 * 8) * 2;
      {
        int row = q32;
        bf16x8 kf = *(const bf16x8*)((char*)Kt[p] + row * 128 + (dk2b ^ ((row & 7) << 4)));
        s0 = __builtin_amdgcn_mfma_f32_32x32x16_bf16(kf, qf[ds], s0, 0, 0, 0);
      }
      {
        int row = 32 + q32;
        bf16x8 kf = *(const bf16x8*)((char*)Kt[p] + row * 128 + (dk2b ^ ((row & 7) << 4)));
        s1 = __builtin_amdgcn_mfma_f32_32x32x16_bf16(kf, qf[ds], s1, 0, 0, 0);
      }
    }
    __builtin_amdgcn_s_setprio(0);

    // --- causal mask (last two tiles only)
    if (kt >= 2 * qt) {
#pragma unroll
      for (int reg = 0; reg < 16; ++reg) {
        int key = k0 + (reg & 3) + 8 * (reg >> 2) + 4 * h5;
        if (key > qrow_g) s0[reg] = -1e30f;
        if (key + 32 > qrow_g) s1[reg] = -1e30f;
      }
    }

    // --- row max: in-register over 32, then one shuffle (lane pair)
    float mx = s0[0];
#pragma unroll
    for (int i = 1; i < 16; ++i) mx = fmaxf(mx, s0[i]);
#pragma unroll
    for (int i = 0; i < 16; ++i) mx = fmaxf(mx, s1[i]);
    mx = fmaxf(mx, __shfl_xor(mx, 32));

    // --- T13 defer-max
    if (!__all(mx <= mrun + 8.0f)) {
      float m_new = fmaxf(mrun, mx);
      float esc = __builtin_amdgcn_exp2f(mrun - m_new);
      mrun = m_new;
      lrun *= esc;
#pragma unroll
      for (int i = 0; i < 16; ++i) { oacc0[i] *= esc; oacc1[i] *= esc; }
    }

    // --- P = exp2(S - m); row sum via one shuffle
    float rsum = 0.f;
#pragma unroll
    for (int i = 0; i < 16; ++i) { s0[i] = __builtin_amdgcn_exp2f(s0[i] - mrun); rsum += s0[i]; }
#pragma unroll
    for (int i = 0; i < 16; ++i) { s1[i] = __builtin_amdgcn_exp2f(s1[i] - mrun); rsum += s1[i]; }
    rsum += __shfl_xor(rsum, 32);
    lrun += rsum;

    // --- build PV B-fragments in-register (cvt_pk + permlane32_swap)
    bf16x8 pf[4];
#pragma unroll
    for (int ks = 0; ks < 4; ++ks) {
      const int base = (ks & 1) * 8;
      unsigned ca, cb, cc, cd;
      if (ks < 2) {
        ca = cvtpk_bf16(s0[base + 0], s0[base + 1]);
        cb = cvtpk_bf16(s0[base + 2], s0[base + 3]);
        cc = cvtpk_bf16(s0[base + 4], s0[base + 5]);
        cd = cvtpk_bf16(s0[base + 6], s0[base + 7]);
      } else {
        ca = cvtpk_bf16(s1[base + 0], s1[base + 1]);
        cb = cvtpk_bf16(s1[base + 2], s1[base + 3]);
        cc = cvtpk_bf16(s1[base + 4], s1[base + 5]);
        cd = cvtpk_bf16(s1[base + 6], s1[base + 7]);
      }
      // vdst.row1 <-> vsrc.row0 (verified R14)
      asm volatile("v_permlane32_swap_b32 %0, %1" : "+v"(ca), "+v"(cc));
      asm volatile("v_permlane32_swap_b32 %0, %1" : "+v"(cb), "+v"(cd));
      union { unsigned u[4]; bf16x8 v; } pw;
      pw.u[0] = ca; pw.u[1] = cb; pw.u[2] = cc; pw.u[3] = cd;
      pf[ks] = pw.v;
    }

    // --- PV: oacc^T[dk][q] += V^T frag x P^T frag
    __builtin_amdgcn_s_setprio(1);
#pragma unroll
    for (int ks = 0; ks < 4; ++ks) {
      int key2b = (ks * 16 + h5 * 8) * 2;
      {
        int row = q32;
        bf16x8 vf = *(const bf16x8*)((char*)Vt[p] + row * 128 + (key2b ^ ((row & 7) << 4)));
        oacc0 = __builtin_amdgcn_mfma_f32_32x32x16_bf16(vf, pf[ks], oacc0, 0, 0, 0);
      }
      {
        int row = 32 + q32;
        bf16x8 vf = *(const bf16x8*)((char*)Vt[p] + row * 128 + (key2b ^ ((row & 7) << 4)));
        oacc1 = __builtin_amdgcn_mfma_f32_32x32x16_bf16(vf, pf[ks], oacc1, 0, 0, 0);
      }
    }
    __builtin_amdgcn_s_setprio(0);
  }  // kt

  // epilogue
  float linv = 1.0f / lrun;
  bf16_t* optr = attn + ((size_t)b * NS + qrow_g) * ND + h * 64;
#pragma unroll
  for (int rr = 0; rr < 4; ++rr) {
    bf16x4 o4a, o4b;
#pragma unroll
    for (int j = 0; j < 4; ++j) {
      o4a[j] = (bf16_t)(oacc0[rr * 4 + j] * linv);
      o4b[j] = (bf16_t)(oacc1[rr * 4 + j] * linv);
    }
    *(bf16x4*)(optr + rr * 8 + h5 * 4) = o4a;
    *(bf16x4*)(optr + 32 + rr * 8 + h5 * 4) = o4b;
  }
}

// ---------------- launch ----------------
extern "C" void kernel_launch(void* const* d_in, const int* in_sizes, int n_in,
                              void* d_out, int out_size, void* d_ws, size_t ws_size,
                              hipStream_t stream) {
  const float* q  = (const float*)d_in[0];
  const float* k  = (const float*)d_in[1];
  const float* v  = (const float*)d_in[2];
  // d_in[3] = mask (int32 tril, implemented analytically)
  const float* Wq = (const float*)d_in[4];
  const float* bq = (const float*)d_in[5];
  const float* Wk = (const float*)d_in[6];
  const float* bk = (const float*)d_in[7];
  const float* Wv = (const float*)d_in[8];
  const float* bv = (const float*)d_in[9];
  const float* Wo = (const float*)d_in[10];
  const float* bo = (const float*)d_in[11];
  float* out = (float*)d_out;

  const size_t NX = (size_t)NB * NS * ND;  // 8388608
  const size_t NW = (size_t)ND * ND;       // 1048576
  char* ws = (char*)d_ws;
  size_t off = 0;
  auto alloc = [&](size_t bytes) {
    char* p = ws + off;
    off += (bytes + 255) & ~(size_t)255;
    return p;
  };
  bf16_t* wqb = (bf16_t*)alloc(NW * 2);
  bf16_t* wkb = (bf16_t*)alloc(NW * 2);
  bf16_t* wvb = (bf16_t*)alloc(NW * 2);
  bf16_t* wob = (bf16_t*)alloc(NW * 2);
  bf16_t* q1  = (bf16_t*)alloc(NX * 2);
  bf16_t* k1  = (bf16_t*)alloc(NX * 2);
  bf16_t* v1t = (bf16_t*)alloc(NX * 2);   // transposed per-head: [bh][dk][s]
  bf16_t* at  = (bf16_t*)alloc(NX * 2);

  dim3 blk(256);
  cvt4_kernel<<<dim3(128, 4), blk, 0, stream>>>(Wq, wqb, Wk, wkb, Wv, wvb, Wo, wob, (long)NW);

  gemm_qkv<<<dim3(1536), dim3(256), 0, stream>>>(
      q, wqb, bq, q1, k, wkb, bk, k1, v, wvb, bv, v1t);

  attn_kernel<<<dim3(1024), dim3(256), 0, stream>>>(q1, k1, v1t, at);

  gemm_bt<<<dim3(256), dim3(512), 0, stream>>>(at, wob, bo, out, NB * NS, ND, ND);
}

// Round 19
// 136.837 us; speedup vs baseline: 1.0796x; 1.0796x over previous
//
#include <hip/hip_runtime.h>
#include <hip/hip_bf16.h>
#include <stdint.h>

// Problem constants
constexpr int NB = 8;     // batch
constexpr int NS = 1024;  // seq
constexpr int ND = 1024;  // model dim
constexpr int NH = 16;    // heads
constexpr int NDK = 64;   // head dim
constexpr int NKT = ND / 64;  // 16 K-tiles per GEMM

typedef __bf16 bf16_t;
typedef __attribute__((ext_vector_type(8))) __bf16 bf16x8;
typedef __attribute__((ext_vector_type(4))) __bf16 bf16x4;
typedef __attribute__((ext_vector_type(4))) float f32x4;
typedef __attribute__((ext_vector_type(16))) float f32x16;

#define GLL16(g, s) __builtin_amdgcn_global_load_lds( \
    (const __attribute__((address_space(1))) void*)(g), \
    (__attribute__((address_space(3))) void*)(s), 16, 0, 0)

__device__ __forceinline__ unsigned cvtpk_bf16(float lo, float hi) {
  unsigned r;
  asm("v_cvt_pk_bf16_f32 %0, %1, %2" : "=v"(r) : "v"(lo), "v"(hi));
  return r;
}

// ---------------- fp32 -> bf16 convert (weights only) ----------------
__device__ __forceinline__ void cvt_body(const float* __restrict__ s,
                                         bf16_t* __restrict__ d, long n) {
  long i0 = (long)(blockIdx.x * blockDim.x + threadIdx.x) * 4;
  long step = (long)gridDim.x * blockDim.x * 4;
  for (long i = i0; i < n; i += step) {
    float4 f = *(const float4*)(s + i);
    bf16x4 o;
    o[0] = (bf16_t)f.x; o[1] = (bf16_t)f.y; o[2] = (bf16_t)f.z; o[3] = (bf16_t)f.w;
    *(bf16x4*)(d + i) = o;
  }
}

__global__ __launch_bounds__(256) void cvt4_kernel(const float* s0, bf16_t* d0,
                                                   const float* s1, bf16_t* d1,
                                                   const float* s2, bf16_t* d2,
                                                   const float* s3, bf16_t* d3, long n) {
  const float* s = blockIdx.y == 0 ? s0 : blockIdx.y == 1 ? s1 : blockIdx.y == 2 ? s2 : s3;
  bf16_t* d = blockIdx.y == 0 ? d0 : blockIdx.y == 1 ? d1 : blockIdx.y == 2 ? d2 : d3;
  cvt_body(s, d, n);
}

// ---------------- QKV GEMM, fused fp32->bf16 A-convert, 128x128 tile -----
// EXACT R16 structure (proven best: 136.6 us total). 256 threads, 4 waves
// (2M x 2N, per-wave 64x64), BK=64, 2 blocks/CU (80KB LDS) — cross-block
// wave slip hides the serial vmcnt->writeA->barrier segment (m114).
// A: reg-staged fp32 distance-2 (faA/faB parity); B: GLL16 XOR-swizzled,
// 3 bufs. Ledger: prologue [A0:8,A1:8,B0:4,B1:4] -> vmcnt(4) keeps B1;
// body(t) issues A(t+2):8 then B(t+2):4, computes, vmcnt(12) retires
// A(t+1)+B(t+1) (never 0 mid-loop), writeA(t+1), lgkm(0)+barrier.
// z==2 (V) writes output transposed per head for attn's GLL V-staging.
__global__ __launch_bounds__(256, 2) void gemm_qkv(
    const float* A0, const bf16_t* W0, const float* b0, bf16_t* C0,
    const float* A1, const bf16_t* W1, const float* b1, bf16_t* C1,
    const float* A2, const bf16_t* W2, const float* b2, bf16_t* C2) {
  __shared__ bf16_t S[5 * 8192];  // A 2x8192 + B 3x8192 elems (80KB)
  const int o = blockIdx.x;
  const int xcd = o & 7, s = o >> 3;   // s in [0,192)
  const int bx = s & 7, u = s >> 3;    // u in [0,24)
  const int zby = xcd + 8 * u;         // 0..191
  const int z = zby >> 6, by = zby & 63;
  const float* A = z == 0 ? A0 : z == 1 ? A1 : A2;
  const bf16_t* W = z == 0 ? W0 : z == 1 ? W1 : W2;
  const float* bb = z == 0 ? b0 : z == 1 ? b1 : b2;
  bf16_t* C = z == 0 ? C0 : z == 1 ? C1 : C2;

  const int tid = threadIdx.x;           // 0..255
  const int l = tid & 63, w = tid >> 6;  // 4 waves
  const int wr = w >> 1, wc = w & 1;     // 2M x 2N
  const int g = l >> 4, r = l & 15;
  const int m0 = by * 128, n0 = bx * 128;
  const int wbase = w * 512;

  bf16_t* Ab = S;            // 2 x 8192 elems
  bf16_t* Bb = S + 16384;    // 3 x 8192 elems

  float4 faA[8], faB[8];
  auto issueA = [&](int t, float4 (&dst)[8]) {
#pragma unroll
    for (int it = 0; it < 4; ++it) {
      const float* p = A + (size_t)(m0 + it * 32 + (tid >> 3)) * ND + t * 64 + (tid & 7) * 8;
      dst[it * 2]     = *(const float4*)p;
      dst[it * 2 + 1] = *(const float4*)(p + 4);
    }
  };
  auto writeA = [&](int ab, float4 (&src)[8]) {
#pragma unroll
    for (int it = 0; it < 4; ++it) {
      int row = it * 32 + (tid >> 3), c = tid & 7;
      bf16x8 ov;
      ov[0] = (bf16_t)src[it * 2].x;     ov[1] = (bf16_t)src[it * 2].y;
      ov[2] = (bf16_t)src[it * 2].z;     ov[3] = (bf16_t)src[it * 2].w;
      ov[4] = (bf16_t)src[it * 2 + 1].x; ov[5] = (bf16_t)src[it * 2 + 1].y;
      ov[6] = (bf16_t)src[it * 2 + 1].z; ov[7] = (bf16_t)src[it * 2 + 1].w;
      *(bf16x8*)(Ab + ab * 8192 + row * 64 + ((c ^ (row & 7)) << 3)) = ov;
    }
  };
  auto stageB = [&](int qb, int t) {
#pragma unroll
    for (int it = 0; it < 4; ++it) {
      int idx = it * 256 + tid;
      int row = idx >> 3, c = (idx & 7) ^ (row & 7);
      GLL16(W + (size_t)(n0 + row) * ND + (t << 6) + c * 8,
            Bb + qb * 8192 + it * 2048 + wbase);
    }
  };

  f32x4 acc[4][4] = {};

  // prologue: queue [A0:8, A1:8, B0:4, B1:4]; vmcnt(4) keeps only B1.
  issueA(0, faA);
  issueA(1, faB);
  stageB(0, 0);
  stageB(1, 1);
  asm volatile("s_waitcnt vmcnt(4)" ::: "memory");
  __builtin_amdgcn_sched_barrier(0);
  writeA(0, faA);
  asm volatile("s_waitcnt lgkmcnt(0)" ::: "memory");
  __builtin_amdgcn_s_barrier();

  auto bodyT = [&](int t, float4 (&fiss)[8], float4 (&fwr)[8]) {
    if (t + 2 < NKT) issueA(t + 2, fiss);
    __builtin_amdgcn_sched_barrier(0);   // pin: A issues before B issues
    if (t + 2 < NKT) stageB((t + 2) % 3, t + 2);
    __builtin_amdgcn_sched_barrier(0);   // pin: issues before compute

    const bf16_t* a_ = Ab + (t & 1) * 8192;
    const bf16_t* b_ = Bb + (t % 3) * 8192;
#pragma unroll
    for (int kk = 0; kk < 2; ++kk) {
      bf16x8 af[4], bw[4];
#pragma unroll
      for (int m = 0; m < 4; ++m) {
        int row = wr * 64 + m * 16 + r;
        af[m] = *(const bf16x8*)(a_ + row * 64 + (((kk * 4 + g) ^ (row & 7)) << 3));
      }
#pragma unroll
      for (int n = 0; n < 4; ++n) {
        int row = wc * 64 + n * 16 + r;
        bw[n] = *(const bf16x8*)(b_ + row * 64 + (((kk * 4 + g) ^ (row & 7)) << 3));
      }
      __builtin_amdgcn_s_setprio(1);
#pragma unroll
      for (int m = 0; m < 4; ++m)
#pragma unroll
        for (int n = 0; n < 4; ++n)
          acc[m][n] = __builtin_amdgcn_mfma_f32_16x16x32_bf16(af[m], bw[n], acc[m][n], 0, 0, 0);
      __builtin_amdgcn_s_setprio(0);
    }

    // retire A(t+1):8 + B(t+1):4; keep A(t+2):8 + B(t+2):4 in flight
    if (t + 2 < NKT)      asm volatile("s_waitcnt vmcnt(12)" ::: "memory");
    else                  asm volatile("s_waitcnt vmcnt(0)" ::: "memory");
    __builtin_amdgcn_sched_barrier(0);   // rule 18: fwr regs read below
    if (t + 1 < NKT) writeA((t + 1) & 1, fwr);
    asm volatile("s_waitcnt lgkmcnt(0)" ::: "memory");
    __builtin_amdgcn_s_barrier();        // publish tile t+1
  };

#pragma unroll 1
  for (int tt = 0; tt < NKT; tt += 2) {  // parity-unrolled: static fa buffers
    bodyT(tt, faA, faB);
    bodyT(tt + 1, faB, faA);
  }

  if (z == 2) {
    // transposed per-head epilogue: v1t[((b*16+h)*64+dk)*1024 + s]
#pragma unroll
    for (int n = 0; n < 4; ++n) {
      int col = n0 + wc * 64 + n * 16 + r;
      int hh = col >> 6, dk = col & 63;
      float bv = bb[col];
#pragma unroll
      for (int m = 0; m < 4; ++m) {
        int row0 = m0 + wr * 64 + m * 16 + g * 4;
        int b_ = row0 >> 10, s0 = row0 & 1023;
        bf16x4 o4;
#pragma unroll
        for (int j = 0; j < 4; ++j) o4[j] = (bf16_t)(acc[m][n][j] + bv);
        *(bf16x4*)(C + (((size_t)b_ * 16 + hh) * 64 + dk) * 1024 + s0) = o4;
      }
    }
  } else {
#pragma unroll
    for (int n = 0; n < 4; ++n) {
      int col = n0 + wc * 64 + n * 16 + r;
      float bv = bb[col];
#pragma unroll
      for (int m = 0; m < 4; ++m) {
        int row0 = m0 + wr * 64 + m * 16 + g * 4;
#pragma unroll
        for (int j = 0; j < 4; ++j)
          C[(size_t)(row0 + j) * ND + col] = (bf16_t)(acc[m][n][j] + bv);
      }
    }
  }
}

// ---------------- O-projection GEMM (R8 structure, proven) ----------------
__global__ __launch_bounds__(512, 2) void gemm_bt(const bf16_t* __restrict__ A,
                                                  const bf16_t* __restrict__ W,
                                                  const float* __restrict__ bias,
                                                  float* __restrict__ Cout,
                                                  int M, int N, int K) {
  __shared__ bf16_t S[3 * 24576];
  const int o = blockIdx.x;
  const int xcd = o & 7, s = o >> 3;   // s in [0,32)
  const int bx = s & 7, u = s >> 3;    // u in [0,4)
  const int by = xcd + 8 * u;

  const int tid = threadIdx.x;
  const int l = tid & 63, w = tid >> 6;
  const int wr = w >> 1, wc = w & 1;
  const int g = l >> 4, r = l & 15;
  const int m0 = by * 256, n0 = bx * 128;
  const int wbase = w * 512;

  auto stageA2 = [&](int q, int t, int half) {
#pragma unroll
    for (int it = half * 2; it < half * 2 + 2; ++it) {
      int idx = it * 512 + tid;
      int row = idx >> 3, c = (idx & 7) ^ (row & 7);
      GLL16(A + (size_t)(m0 + row) * K + (t << 6) + c * 8,
            S + q * 24576 + it * 4096 + wbase);
    }
  };
  auto stageB2 = [&](int q, int t) {
#pragma unroll
    for (int it = 0; it < 2; ++it) {
      int idx = it * 512 + tid;
      int row = idx >> 3, c = (idx & 7) ^ (row & 7);
      GLL16(W + (size_t)(n0 + row) * K + (t << 6) + c * 8,
            S + q * 24576 + 16384 + it * 4096 + wbase);
    }
  };

  f32x4 acc[4][4] = {};
  const int NKT2 = K >> 6;

  stageA2(0, 0, 0); stageA2(0, 0, 1); stageB2(0, 0);
  stageA2(1, 1, 0); stageA2(1, 1, 1); stageB2(1, 1);

  int q = 0;
  for (int t = 0; t < NKT2; ++t) {
    const bool pf = (t + 2 < NKT2);
    int q2 = q + 2; if (q2 >= 3) q2 -= 3;

    if (t + 1 < NKT2) asm volatile("s_waitcnt vmcnt(6)" ::: "memory");
    else              asm volatile("s_waitcnt vmcnt(0)" ::: "memory");
    __builtin_amdgcn_s_barrier();

    const bf16_t* a_ = S + q * 24576;
    const bf16_t* b_ = a_ + 16384;

#pragma unroll
    for (int kk = 0; kk < 2; ++kk) {
      bf16x8 bw[4];
#pragma unroll
      for (int n = 0; n < 4; ++n) {
        int row = wc * 64 + n * 16 + r;
        bw[n] = *(const bf16x8*)(b_ + row * 64 + (((kk * 4 + g) ^ (row & 7)) << 3));
      }
#pragma unroll
      for (int mh = 0; mh < 2; ++mh) {
        bf16x8 af[2];
#pragma unroll
        for (int i = 0; i < 2; ++i) {
          int row = wr * 64 + (mh * 2 + i) * 16 + r;
          af[i] = *(const bf16x8*)(a_ + row * 64 + (((kk * 4 + g) ^ (row & 7)) << 3));
        }
        if (pf) {
          int ph = kk * 2 + mh;
          if (ph == 0)      stageA2(q2, t + 2, 0);
          else if (ph == 1) stageA2(q2, t + 2, 1);
          else if (ph == 2) stageB2(q2, t + 2);
        }
        __builtin_amdgcn_s_barrier();
        asm volatile("s_waitcnt lgkmcnt(0)" ::: "memory");
        __builtin_amdgcn_sched_barrier(0);
        __builtin_amdgcn_s_setprio(1);
#pragma unroll
        for (int i = 0; i < 2; ++i)
#pragma unroll
          for (int n = 0; n < 4; ++n)
            acc[mh * 2 + i][n] = __builtin_amdgcn_mfma_f32_16x16x32_bf16(
                af[i], bw[n], acc[mh * 2 + i][n], 0, 0, 0);
        __builtin_amdgcn_s_setprio(0);
        __builtin_amdgcn_sched_barrier(0);
      }
    }
    ++q; if (q >= 3) q -= 3;
  }

#pragma unroll
  for (int n = 0; n < 4; ++n) {
    int col = n0 + wc * 64 + n * 16 + r;
    float bv = bias[col];
#pragma unroll
    for (int m = 0; m < 4; ++m) {
      int row0 = m0 + wr * 64 + m * 16 + g * 4;
#pragma unroll
      for (int j = 0; j < 4; ++j)
        Cout[(size_t)(row0 + j) * N + col] = acc[m][n][j] + bv;
    }
  }
}

// ---------------- causal flash attention (R14 exact: 32x32, paired) -------
// 512 blocks (pair {p,7-p} -> uniform 18 iters), 2 blocks/CU — the balanced
// configuration (R18's unpaired 4/CU variant regressed on co-residency
// imbalance). 4 waves x 32 q-rows, KVBLK=64, swapped QK^T, in-register P
// via cvt_pk + permlane32_swap, T13 defer-max.
__global__ __launch_bounds__(256, 2) void attn_kernel(const bf16_t* __restrict__ Q1,
                                                      const bf16_t* __restrict__ K1,
                                                      const bf16_t* __restrict__ V1t,
                                                      bf16_t* __restrict__ attn) {
  __shared__ bf16_t Kt[2][64 * 64];
  __shared__ bf16_t Vt[2][64 * 64];

  const int tid = threadIdx.x;           // 0..255
  const int l = tid & 63, w = tid >> 6;  // 4 waves
  const int q32 = l & 31, h5 = l >> 5;

  // XCD swizzle: 512 blocks; each (b,h)'s 4 blocks land on one XCD.
  const int o = blockIdx.x;
  const int os = (o & 7) * 64 + (o >> 3);
  const int pair = os & 3, hb = os >> 2;
  const int h = hb & 15, b = hb >> 4;

  constexpr float SC = 0.18033688011112042f;  // 0.125 * log2(e)
  const bf16_t* vbase = V1t + ((size_t)(b * 16 + h) * 64) * 1024;

  auto stageKV = [&](int kt2, int pb) {
    const int k0 = kt2 * 64;
#pragma unroll
    for (int it = 0; it < 2; ++it) {
      int idx = it * 256 + tid;
      int row = idx >> 3, c = (idx & 7) ^ (row & 7);
      GLL16(K1 + ((size_t)b * NS + k0 + row) * ND + h * 64 + c * 8,
            &Kt[pb][it * 2048 + w * 512]);
      GLL16(vbase + (size_t)row * 1024 + k0 + c * 8,
            &Vt[pb][it * 2048 + w * 512]);
    }
  };

  for (int ph = 0; ph < 2; ++ph) {
    const int qt = ph ? (7 - pair) : pair;        // 128-row q-tile index
    const int qrow_g = qt * 128 + w * 32 + q32;   // this lane's q-row

    const bf16_t* qptr = Q1 + ((size_t)b * NS + qrow_g) * ND + h * 64;
    bf16x8 qf[4];
#pragma unroll
    for (int ds = 0; ds < 4; ++ds) {
      qf[ds] = *(const bf16x8*)(qptr + ds * 16 + h5 * 8);
#pragma unroll
      for (int i = 0; i < 8; ++i) qf[ds][i] = (bf16_t)((float)qf[ds][i] * SC);
    }

    float mrun = -1e30f, lrun = 0.f;
    f32x16 oacc0 = {}, oacc1 = {};

    __syncthreads();  // prior phase's readers done before restaging buf 0

    const int nkt = 2 * qt + 2;
    stageKV(0, 0);    // prologue

    for (int kt = 0; kt < nkt; ++kt) {
      const int p = kt & 1;
      const int k0 = kt * 64;

      __syncthreads();  // drains GLLs for tile kt (covered by prev compute)

      if (kt + 1 < nkt) stageKV(kt + 1, p ^ 1);

      // --- QK^T: s0 = keys k0..k0+31, s1 = keys k0+32..k0+63 (rows), col=q
      f32x16 s0 = {}, s1 = {};
      __builtin_amdgcn_s_setprio(1);
#pragma unroll
      for (int ds = 0; ds < 4; ++ds) {
        int dk2b = (ds * 16 + h5 * 8) * 2;
        {
          int row = q32;
          bf16x8 kf = *(const bf16x8*)((char*)Kt[p] + row * 128 + (dk2b ^ ((row & 7) << 4)));
          s0 = __builtin_amdgcn_mfma_f32_32x32x16_bf16(kf, qf[ds], s0, 0, 0, 0);
        }
        {
          int row = 32 + q32;
          bf16x8 kf = *(const bf16x8*)((char*)Kt[p] + row * 128 + (dk2b ^ ((row & 7) << 4)));
          s1 = __builtin_amdgcn_mfma_f32_32x32x16_bf16(kf, qf[ds], s1, 0, 0, 0);
        }
      }
      __builtin_amdgcn_s_setprio(0);

      // --- causal mask (last two tiles only)
      if (kt >= 2 * qt) {
#pragma unroll
        for (int reg = 0; reg < 16; ++reg) {
          int key = k0 + (reg & 3) + 8 * (reg >> 2) + 4 * h5;
          if (key > qrow_g) s0[reg] = -1e30f;
          if (key + 32 > qrow_g) s1[reg] = -1e30f;
        }
      }

      // --- row max: in-register over 32, then one shuffle (lane pair)
      float mx = s0[0];
#pragma unroll
      for (int i = 1; i < 16; ++i) mx = fmaxf(mx, s0[i]);
#pragma unroll
      for (int i = 0; i < 16; ++i) mx = fmaxf(mx, s1[i]);
      mx = fmaxf(mx, __shfl_xor(mx, 32));

      // --- T13 defer-max
      if (!__all(mx <= mrun + 8.0f)) {
        float m_new = fmaxf(mrun, mx);
        float esc = __builtin_amdgcn_exp2f(mrun - m_new);
        mrun = m_new;
        lrun *= esc;
#pragma unroll
        for (int i = 0; i < 16; ++i) { oacc0[i] *= esc; oacc1[i] *= esc; }
      }

      // --- P = exp2(S - m); row sum via one shuffle
      float rsum = 0.f;
#pragma unroll
      for (int i = 0; i < 16; ++i) { s0[i] = __builtin_amdgcn_exp2f(s0[i] - mrun); rsum += s0[i]; }
#pragma unroll
      for (int i = 0; i < 16; ++i) { s1[i] = __builtin_amdgcn_exp2f(s1[i] - mrun); rsum += s1[i]; }
      rsum += __shfl_xor(rsum, 32);
      lrun += rsum;

      // --- build PV B-fragments in-register (cvt_pk + permlane32_swap)
      bf16x8 pf[4];
#pragma unroll
      for (int ks = 0; ks < 4; ++ks) {
        const int base = (ks & 1) * 8;
        unsigned ca, cb, cc, cd;
        if (ks < 2) {
          ca = cvtpk_bf16(s0[base + 0], s0[base + 1]);
          cb = cvtpk_bf16(s0[base + 2], s0[base + 3]);
          cc = cvtpk_bf16(s0[base + 4], s0[base + 5]);
          cd = cvtpk_bf16(s0[base + 6], s0[base + 7]);
        } else {
          ca = cvtpk_bf16(s1[base + 0], s1[base + 1]);
          cb = cvtpk_bf16(s1[base + 2], s1[base + 3]);
          cc = cvtpk_bf16(s1[base + 4], s1[base + 5]);
          cd = cvtpk_bf16(s1[base + 6], s1[base + 7]);
        }
        // vdst.row1 <-> vsrc.row0 (verified R14)
        asm volatile("v_permlane32_swap_b32 %0, %1" : "+v"(ca), "+v"(cc));
        asm volatile("v_permlane32_swap_b32 %0, %1" : "+v"(cb), "+v"(cd));
        union { unsigned u[4]; bf16x8 v; } pw;
        pw.u[0] = ca; pw.u[1] = cb; pw.u[2] = cc; pw.u[3] = cd;
        pf[ks] = pw.v;
      }

      // --- PV: oacc^T[dk][q] += V^T frag x P^T frag
      __builtin_amdgcn_s_setprio(1);
#pragma unroll
      for (int ks = 0; ks < 4; ++ks) {
        int key2b = (ks * 16 + h5 * 8) * 2;
        {
          int row = q32;
          bf16x8 vf = *(const bf16x8*)((char*)Vt[p] + row * 128 + (key2b ^ ((row & 7) << 4)));
          oacc0 = __builtin_amdgcn_mfma_f32_32x32x16_bf16(vf, pf[ks], oacc0, 0, 0, 0);
        }
        {
          int row = 32 + q32;
          bf16x8 vf = *(const bf16x8*)((char*)Vt[p] + row * 128 + (key2b ^ ((row & 7) << 4)));
          oacc1 = __builtin_amdgcn_mfma_f32_32x32x16_bf16(vf, pf[ks], oacc1, 0, 0, 0);
        }
      }
      __builtin_amdgcn_s_setprio(0);
    }  // kt

    // epilogue
    float linv = 1.0f / lrun;
    bf16_t* optr = attn + ((size_t)b * NS + qrow_g) * ND + h * 64;
#pragma unroll
    for (int rr = 0; rr < 4; ++rr) {
      bf16x4 o4a, o4b;
#pragma unroll
      for (int j = 0; j < 4; ++j) {
        o4a[j] = (bf16_t)(oacc0[rr * 4 + j] * linv);
        o4b[j] = (bf16_t)(oacc1[rr * 4 + j] * linv);
      }
      *(bf16x4*)(optr + rr * 8 + h5 * 4) = o4a;
      *(bf16x4*)(optr + 32 + rr * 8 + h5 * 4) = o4b;
    }
  }  // ph
}

// ---------------- launch ----------------
extern "C" void kernel_launch(void* const* d_in, const int* in_sizes, int n_in,
                              void* d_out, int out_size, void* d_ws, size_t ws_size,
                              hipStream_t stream) {
  const float* q  = (const float*)d_in[0];
  const float* k  = (const float*)d_in[1];
  const float* v  = (const float*)d_in[2];
  // d_in[3] = mask (int32 tril, implemented analytically)
  const float* Wq = (const float*)d_in[4];
  const float* bq = (const float*)d_in[5];
  const float* Wk = (const float*)d_in[6];
  const float* bk = (const float*)d_in[7];
  const float* Wv = (const float*)d_in[8];
  const float* bv = (const float*)d_in[9];
  const float* Wo = (const float*)d_in[10];
  const float* bo = (const float*)d_in[11];
  float* out = (float*)d_out;

  const size_t NX = (size_t)NB * NS * ND;  // 8388608
  const size_t NW = (size_t)ND * ND;       // 1048576
  char* ws = (char*)d_ws;
  size_t off = 0;
  auto alloc = [&](size_t bytes) {
    char* p = ws + off;
    off += (bytes + 255) & ~(size_t)255;
    return p;
  };
  bf16_t* wqb = (bf16_t*)alloc(NW * 2);
  bf16_t* wkb = (bf16_t*)alloc(NW * 2);
  bf16_t* wvb = (bf16_t*)alloc(NW * 2);
  bf16_t* wob = (bf16_t*)alloc(NW * 2);
  bf16_t* q1  = (bf16_t*)alloc(NX * 2);
  bf16_t* k1  = (bf16_t*)alloc(NX * 2);
  bf16_t* v1t = (bf16_t*)alloc(NX * 2);   // transposed per-head: [bh][dk][s]
  bf16_t* at  = (bf16_t*)alloc(NX * 2);

  dim3 blk(256);
  cvt4_kernel<<<dim3(128, 4), blk, 0, stream>>>(Wq, wqb, Wk, wkb, Wv, wvb, Wo, wob, (long)NW);

  gemm_qkv<<<dim3(1536), dim3(256), 0, stream>>>(
      q, wqb, bq, q1, k, wkb, bk, k1, v, wvb, bv, v1t);

  attn_kernel<<<dim3(512), dim3(256), 0, stream>>>(q1, k1, v1t, at);

  gemm_bt<<<dim3(256), dim3(512), 0, stream>>>(at, wob, bo, out, NB * NS, ND, ND);
}

// Round 21
// 135.838 us; speedup vs baseline: 1.0875x; 1.0074x over previous
//
#include <hip/hip_runtime.h>
#include <hip/hip_bf16.h>
#include <stdint.h>

// Problem constants
constexpr int NB = 8;     // batch
constexpr int NS = 1024;  // seq
constexpr int ND = 1024;  // model dim
constexpr int NH = 16;    // heads
constexpr int NDK = 64;   // head dim
constexpr int NKT = ND / 64;  // 16 K-tiles per GEMM

typedef __bf16 bf16_t;
typedef __attribute__((ext_vector_type(8))) __bf16 bf16x8;
typedef __attribute__((ext_vector_type(4))) __bf16 bf16x4;
typedef __attribute__((ext_vector_type(4))) float f32x4;
typedef __attribute__((ext_vector_type(16))) float f32x16;

#define GLL16(g, s) __builtin_amdgcn_global_load_lds( \
    (const __attribute__((address_space(1))) void*)(g), \
    (__attribute__((address_space(3))) void*)(s), 16, 0, 0)

__device__ __forceinline__ unsigned cvtpk_bf16(float lo, float hi) {
  unsigned r;
  asm("v_cvt_pk_bf16_f32 %0, %1, %2" : "=v"(r) : "v"(lo), "v"(hi));
  return r;
}

// ---------------- fp32 -> bf16 convert (weights only) ----------------
__device__ __forceinline__ void cvt_body(const float* __restrict__ s,
                                         bf16_t* __restrict__ d, long n) {
  long i0 = (long)(blockIdx.x * blockDim.x + threadIdx.x) * 4;
  long step = (long)gridDim.x * blockDim.x * 4;
  for (long i = i0; i < n; i += step) {
    float4 f = *(const float4*)(s + i);
    bf16x4 o;
    o[0] = (bf16_t)f.x; o[1] = (bf16_t)f.y; o[2] = (bf16_t)f.z; o[3] = (bf16_t)f.w;
    *(bf16x4*)(d + i) = o;
  }
}

__global__ __launch_bounds__(256) void cvt4_kernel(const float* s0, bf16_t* d0,
                                                   const float* s1, bf16_t* d1,
                                                   const float* s2, bf16_t* d2,
                                                   const float* s3, bf16_t* d3, long n) {
  const float* s = blockIdx.y == 0 ? s0 : blockIdx.y == 1 ? s1 : blockIdx.y == 2 ? s2 : s3;
  bf16_t* d = blockIdx.y == 0 ? d0 : blockIdx.y == 1 ? d1 : blockIdx.y == 2 ? d2 : d3;
  cvt_body(s, d, n);
}

// ---------------- QKV GEMM, fused fp32->bf16 A-convert, 128x128 tile -----
// EXACT R16 structure (proven best). 256 threads, 4 waves (2M x 2N), BK=64,
// 2 blocks/CU (80KB LDS). A: reg-staged fp32 distance-2 (faA/faB parity);
// B: GLL16 XOR-swizzled, 3 bufs. Ledger: prologue [A0:8,A1:8,B0:4,B1:4] ->
// vmcnt(4) keeps B1; body(t) issues A(t+2):8 then B(t+2):4, computes,
// vmcnt(12) retires A(t+1)+B(t+1) (never 0 mid-loop), writeA(t+1),
// lgkm(0)+barrier. z==2 (V) writes output transposed per head.
__global__ __launch_bounds__(256, 2) void gemm_qkv(
    const float* A0, const bf16_t* W0, const float* b0, bf16_t* C0,
    const float* A1, const bf16_t* W1, const float* b1, bf16_t* C1,
    const float* A2, const bf16_t* W2, const float* b2, bf16_t* C2) {
  __shared__ bf16_t S[5 * 8192];  // A 2x8192 + B 3x8192 elems (80KB)
  const int o = blockIdx.x;
  const int xcd = o & 7, s = o >> 3;   // s in [0,192)
  const int bx = s & 7, u = s >> 3;    // u in [0,24)
  const int zby = xcd + 8 * u;         // 0..191
  const int z = zby >> 6, by = zby & 63;
  const float* A = z == 0 ? A0 : z == 1 ? A1 : A2;
  const bf16_t* W = z == 0 ? W0 : z == 1 ? W1 : W2;
  const float* bb = z == 0 ? b0 : z == 1 ? b1 : b2;
  bf16_t* C = z == 0 ? C0 : z == 1 ? C1 : C2;

  const int tid = threadIdx.x;           // 0..255
  const int l = tid & 63, w = tid >> 6;  // 4 waves
  const int wr = w >> 1, wc = w & 1;     // 2M x 2N
  const int g = l >> 4, r = l & 15;
  const int m0 = by * 128, n0 = bx * 128;
  const int wbase = w * 512;

  bf16_t* Ab = S;            // 2 x 8192 elems
  bf16_t* Bb = S + 16384;    // 3 x 8192 elems

  float4 faA[8], faB[8];
  auto issueA = [&](int t, float4 (&dst)[8]) {
#pragma unroll
    for (int it = 0; it < 4; ++it) {
      const float* p = A + (size_t)(m0 + it * 32 + (tid >> 3)) * ND + t * 64 + (tid & 7) * 8;
      dst[it * 2]     = *(const float4*)p;
      dst[it * 2 + 1] = *(const float4*)(p + 4);
    }
  };
  auto writeA = [&](int ab, float4 (&src)[8]) {
#pragma unroll
    for (int it = 0; it < 4; ++it) {
      int row = it * 32 + (tid >> 3), c = tid & 7;
      bf16x8 ov;
      ov[0] = (bf16_t)src[it * 2].x;     ov[1] = (bf16_t)src[it * 2].y;
      ov[2] = (bf16_t)src[it * 2].z;     ov[3] = (bf16_t)src[it * 2].w;
      ov[4] = (bf16_t)src[it * 2 + 1].x; ov[5] = (bf16_t)src[it * 2 + 1].y;
      ov[6] = (bf16_t)src[it * 2 + 1].z; ov[7] = (bf16_t)src[it * 2 + 1].w;
      *(bf16x8*)(Ab + ab * 8192 + row * 64 + ((c ^ (row & 7)) << 3)) = ov;
    }
  };
  auto stageB = [&](int qb, int t) {
#pragma unroll
    for (int it = 0; it < 4; ++it) {
      int idx = it * 256 + tid;
      int row = idx >> 3, c = (idx & 7) ^ (row & 7);
      GLL16(W + (size_t)(n0 + row) * ND + (t << 6) + c * 8,
            Bb + qb * 8192 + it * 2048 + wbase);
    }
  };

  f32x4 acc[4][4] = {};

  // prologue: queue [A0:8, A1:8, B0:4, B1:4]; vmcnt(4) keeps only B1.
  issueA(0, faA);
  issueA(1, faB);
  stageB(0, 0);
  stageB(1, 1);
  asm volatile("s_waitcnt vmcnt(4)" ::: "memory");
  __builtin_amdgcn_sched_barrier(0);
  writeA(0, faA);
  asm volatile("s_waitcnt lgkmcnt(0)" ::: "memory");
  __builtin_amdgcn_s_barrier();

  auto bodyT = [&](int t, float4 (&fiss)[8], float4 (&fwr)[8]) {
    if (t + 2 < NKT) issueA(t + 2, fiss);
    __builtin_amdgcn_sched_barrier(0);   // pin: A issues before B issues
    if (t + 2 < NKT) stageB((t + 2) % 3, t + 2);
    __builtin_amdgcn_sched_barrier(0);   // pin: issues before compute

    const bf16_t* a_ = Ab + (t & 1) * 8192;
    const bf16_t* b_ = Bb + (t % 3) * 8192;
#pragma unroll
    for (int kk = 0; kk < 2; ++kk) {
      bf16x8 af[4], bw[4];
#pragma unroll
      for (int m = 0; m < 4; ++m) {
        int row = wr * 64 + m * 16 + r;
        af[m] = *(const bf16x8*)(a_ + row * 64 + (((kk * 4 + g) ^ (row & 7)) << 3));
      }
#pragma unroll
      for (int n = 0; n < 4; ++n) {
        int row = wc * 64 + n * 16 + r;
        bw[n] = *(const bf16x8*)(b_ + row * 64 + (((kk * 4 + g) ^ (row & 7)) << 3));
      }
      __builtin_amdgcn_s_setprio(1);
#pragma unroll
      for (int m = 0; m < 4; ++m)
#pragma unroll
        for (int n = 0; n < 4; ++n)
          acc[m][n] = __builtin_amdgcn_mfma_f32_16x16x32_bf16(af[m], bw[n], acc[m][n], 0, 0, 0);
      __builtin_amdgcn_s_setprio(0);
    }

    // retire A(t+1):8 + B(t+1):4; keep A(t+2):8 + B(t+2):4 in flight
    if (t + 2 < NKT)      asm volatile("s_waitcnt vmcnt(12)" ::: "memory");
    else                  asm volatile("s_waitcnt vmcnt(0)" ::: "memory");
    __builtin_amdgcn_sched_barrier(0);   // rule 18: fwr regs read below
    if (t + 1 < NKT) writeA((t + 1) & 1, fwr);
    asm volatile("s_waitcnt lgkmcnt(0)" ::: "memory");
    __builtin_amdgcn_s_barrier();        // publish tile t+1
  };

#pragma unroll 1
  for (int tt = 0; tt < NKT; tt += 2) {  // parity-unrolled: static fa buffers
    bodyT(tt, faA, faB);
    bodyT(tt + 1, faB, faA);
  }

  if (z == 2) {
    // transposed per-head epilogue: v1t[((b*16+h)*64+dk)*1024 + s]
#pragma unroll
    for (int n = 0; n < 4; ++n) {
      int col = n0 + wc * 64 + n * 16 + r;
      int hh = col >> 6, dk = col & 63;
      float bv = bb[col];
#pragma unroll
      for (int m = 0; m < 4; ++m) {
        int row0 = m0 + wr * 64 + m * 16 + g * 4;
        int b_ = row0 >> 10, s0 = row0 & 1023;
        bf16x4 o4;
#pragma unroll
        for (int j = 0; j < 4; ++j) o4[j] = (bf16_t)(acc[m][n][j] + bv);
        *(bf16x4*)(C + (((size_t)b_ * 16 + hh) * 64 + dk) * 1024 + s0) = o4;
      }
    }
  } else {
#pragma unroll
    for (int n = 0; n < 4; ++n) {
      int col = n0 + wc * 64 + n * 16 + r;
      float bv = bb[col];
#pragma unroll
      for (int m = 0; m < 4; ++m) {
        int row0 = m0 + wr * 64 + m * 16 + g * 4;
#pragma unroll
        for (int j = 0; j < 4; ++j)
          C[(size_t)(row0 + j) * ND + col] = (bf16_t)(acc[m][n][j] + bv);
      }
    }
  }
}

// ---------------- O-projection GEMM (R21: fixed ledger, pure-GLL) --------
// 128x128 tile, 256 threads, 4 waves (2M x 2N), BK=64, 2 blocks/CU (80KB).
// A (bf16 attn output): GLL16, 2 bufs, DISTANCE-1. B: GLL16, 3 bufs,
// DISTANCE-2. FIXED ledger (R20 bug: prologue staged A1 AND body(0)
// re-issued it, so the steady wait never retired B(t+1) -> race):
// prologue stages A(0):4, B(0):4, B(1):4 -> vmcnt(4) retires A0,B0
// (keeps B1) -> barrier. body(t): issue A(t+1):4 then B(t+2):4 ->
// compute(t) -> in-flight = B(t+1):4, A(t+1):4, B(t+2):4 = 12 ->
// vmcnt(4) retires exactly B(t+1)+A(t+1), keeps B(t+2) (never 0
// mid-loop; tails t=14/15 -> vmcnt(0)) -> lgkm(0) -> barrier.
// WAR: A(t+1)->buf (t+1)&1, B(t+2)->buf (t+2)%3 were last read by
// compute(t-1), drained before its closing barrier; issues after it.
__global__ __launch_bounds__(256, 2) void gemm_bt(const bf16_t* __restrict__ A,
                                                  const bf16_t* __restrict__ W,
                                                  const float* __restrict__ bias,
                                                  float* __restrict__ Cout) {
  __shared__ bf16_t S[5 * 8192];  // A 2x8192 + B 3x8192 elems (80KB)
  const int o = blockIdx.x;
  const int xcd = o & 7, s = o >> 3;   // s in [0,64)
  const int bx = s & 7, u = s >> 3;    // u in [0,8)
  const int by = xcd + 8 * u;          // all bx of one by share an XCD

  const int tid = threadIdx.x;           // 0..255
  const int l = tid & 63, w = tid >> 6;  // 4 waves
  const int wr = w >> 1, wc = w & 1;     // 2M x 2N
  const int g = l >> 4, r = l & 15;
  const int m0 = by * 128, n0 = bx * 128;
  const int wbase = w * 512;

  bf16_t* Ab = S;            // 2 x 8192 elems
  bf16_t* Bb = S + 16384;    // 3 x 8192 elems

  auto stageA = [&](int qb, int t) {
#pragma unroll
    for (int it = 0; it < 4; ++it) {
      int idx = it * 256 + tid;
      int row = idx >> 3, c = (idx & 7) ^ (row & 7);
      GLL16(A + (size_t)(m0 + row) * ND + (t << 6) + c * 8,
            Ab + qb * 8192 + it * 2048 + wbase);
    }
  };
  auto stageB = [&](int qb, int t) {
#pragma unroll
    for (int it = 0; it < 4; ++it) {
      int idx = it * 256 + tid;
      int row = idx >> 3, c = (idx & 7) ^ (row & 7);
      GLL16(W + (size_t)(n0 + row) * ND + (t << 6) + c * 8,
            Bb + qb * 8192 + it * 2048 + wbase);
    }
  };

  f32x4 acc[4][4] = {};

  // prologue: queue [A0:4, B0:4, B1:4]; vmcnt(4) retires A0,B0 (keeps B1).
  stageA(0, 0);
  stageB(0, 0);
  stageB(1, 1);
  asm volatile("s_waitcnt vmcnt(4)" ::: "memory");
  __builtin_amdgcn_s_barrier();

  for (int t = 0; t < NKT; ++t) {
    if (t + 1 < NKT) stageA((t + 1) & 1, t + 1);
    __builtin_amdgcn_sched_barrier(0);   // pin: A issues before B issues
    if (t + 2 < NKT) stageB((t + 2) % 3, t + 2);
    __builtin_amdgcn_sched_barrier(0);   // pin: issues before compute

    const bf16_t* a_ = Ab + (t & 1) * 8192;
    const bf16_t* b_ = Bb + (t % 3) * 8192;
#pragma unroll
    for (int kk = 0; kk < 2; ++kk) {
      bf16x8 af[4], bw[4];
#pragma unroll
      for (int m = 0; m < 4; ++m) {
        int row = wr * 64 + m * 16 + r;
        af[m] = *(const bf16x8*)(a_ + row * 64 + (((kk * 4 + g) ^ (row & 7)) << 3));
      }
#pragma unroll
      for (int n = 0; n < 4; ++n) {
        int row = wc * 64 + n * 16 + r;
        bw[n] = *(const bf16x8*)(b_ + row * 64 + (((kk * 4 + g) ^ (row & 7)) << 3));
      }
      __builtin_amdgcn_s_setprio(1);
#pragma unroll
      for (int m = 0; m < 4; ++m)
#pragma unroll
        for (int n = 0; n < 4; ++n)
          acc[m][n] = __builtin_amdgcn_mfma_f32_16x16x32_bf16(af[m], bw[n], acc[m][n], 0, 0, 0);
      __builtin_amdgcn_s_setprio(0);
    }

    // retire B(t+1)+A(t+1) (tile t+1 complete); keep only B(t+2) in flight
    if (t + 2 < NKT) asm volatile("s_waitcnt vmcnt(4)" ::: "memory");
    else             asm volatile("s_waitcnt vmcnt(0)" ::: "memory");
    asm volatile("s_waitcnt lgkmcnt(0)" ::: "memory");
    __builtin_amdgcn_s_barrier();        // publish tile t+1
  }

#pragma unroll
  for (int n = 0; n < 4; ++n) {
    int col = n0 + wc * 64 + n * 16 + r;
    float bv = bias[col];
#pragma unroll
    for (int m = 0; m < 4; ++m) {
      int row0 = m0 + wr * 64 + m * 16 + g * 4;
#pragma unroll
      for (int j = 0; j < 4; ++j)
        Cout[(size_t)(row0 + j) * ND + col] = acc[m][n][j] + bv;
    }
  }
}

// ---------------- causal flash attention (R14 exact: 32x32, paired) -------
__global__ __launch_bounds__(256, 2) void attn_kernel(const bf16_t* __restrict__ Q1,
                                                      const bf16_t* __restrict__ K1,
                                                      const bf16_t* __restrict__ V1t,
                                                      bf16_t* __restrict__ attn) {
  __shared__ bf16_t Kt[2][64 * 64];
  __shared__ bf16_t Vt[2][64 * 64];

  const int tid = threadIdx.x;           // 0..255
  const int l = tid & 63, w = tid >> 6;  // 4 waves
  const int q32 = l & 31, h5 = l >> 5;

  // XCD swizzle: 512 blocks; each (b,h)'s 4 blocks land on one XCD.
  const int o = blockIdx.x;
  const int os = (o & 7) * 64 + (o >> 3);
  const int pair = os & 3, hb = os >> 2;
  const int h = hb & 15, b = hb >> 4;

  constexpr float SC = 0.18033688011112042f;  // 0.125 * log2(e)
  const bf16_t* vbase = V1t + ((size_t)(b * 16 + h) * 64) * 1024;

  auto stageKV = [&](int kt2, int pb) {
    const int k0 = kt2 * 64;
#pragma unroll
    for (int it = 0; it < 2; ++it) {
      int idx = it * 256 + tid;
      int row = idx >> 3, c = (idx & 7) ^ (row & 7);
      GLL16(K1 + ((size_t)b * NS + k0 + row) * ND + h * 64 + c * 8,
            &Kt[pb][it * 2048 + w * 512]);
      GLL16(vbase + (size_t)row * 1024 + k0 + c * 8,
            &Vt[pb][it * 2048 + w * 512]);
    }
  };

  for (int ph = 0; ph < 2; ++ph) {
    const int qt = ph ? (7 - pair) : pair;        // 128-row q-tile index
    const int qrow_g = qt * 128 + w * 32 + q32;   // this lane's q-row

    const bf16_t* qptr = Q1 + ((size_t)b * NS + qrow_g) * ND + h * 64;
    bf16x8 qf[4];
#pragma unroll
    for (int ds = 0; ds < 4; ++ds) {
      qf[ds] = *(const bf16x8*)(qptr + ds * 16 + h5 * 8);
#pragma unroll
      for (int i = 0; i < 8; ++i) qf[ds][i] = (bf16_t)((float)qf[ds][i] * SC);
    }

    float mrun = -1e30f, lrun = 0.f;
    f32x16 oacc0 = {}, oacc1 = {};

    __syncthreads();  // prior phase's readers done before restaging buf 0

    const int nkt = 2 * qt + 2;
    stageKV(0, 0);    // prologue

    for (int kt = 0; kt < nkt; ++kt) {
      const int p = kt & 1;
      const int k0 = kt * 64;

      __syncthreads();  // drains GLLs for tile kt (covered by prev compute)

      if (kt + 1 < nkt) stageKV(kt + 1, p ^ 1);

      // --- QK^T: s0 = keys k0..k0+31, s1 = keys k0+32..k0+63 (rows), col=q
      f32x16 s0 = {}, s1 = {};
      __builtin_amdgcn_s_setprio(1);
#pragma unroll
      for (int ds = 0; ds < 4; ++ds) {
        int dk2b = (ds * 16 + h5 * 8) * 2;
        {
          int row = q32;
          bf16x8 kf = *(const bf16x8*)((char*)Kt[p] + row * 128 + (dk2b ^ ((row & 7) << 4)));
          s0 = __builtin_amdgcn_mfma_f32_32x32x16_bf16(kf, qf[ds], s0, 0, 0, 0);
        }
        {
          int row = 32 + q32;
          bf16x8 kf = *(const bf16x8*)((char*)Kt[p] + row * 128 + (dk2b ^ ((row & 7) << 4)));
          s1 = __builtin_amdgcn_mfma_f32_32x32x16_bf16(kf, qf[ds], s1, 0, 0, 0);
        }
      }
      __builtin_amdgcn_s_setprio(0);

      // --- causal mask (last two tiles only)
      if (kt >= 2 * qt) {
#pragma unroll
        for (int reg = 0; reg < 16; ++reg) {
          int key = k0 + (reg & 3) + 8 * (reg >> 2) + 4 * h5;
          if (key > qrow_g) s0[reg] = -1e30f;
          if (key + 32 > qrow_g) s1[reg] = -1e30f;
        }
      }

      // --- row max: in-register over 32, then one shuffle (lane pair)
      float mx = s0[0];
#pragma unroll
      for (int i = 1; i < 16; ++i) mx = fmaxf(mx, s0[i]);
#pragma unroll
      for (int i = 0; i < 16; ++i) mx = fmaxf(mx, s1[i]);
      mx = fmaxf(mx, __shfl_xor(mx, 32));

      // --- T13 defer-max
      if (!__all(mx <= mrun + 8.0f)) {
        float m_new = fmaxf(mrun, mx);
        float esc = __builtin_amdgcn_exp2f(mrun - m_new);
        mrun = m_new;
        lrun *= esc;
#pragma unroll
        for (int i = 0; i < 16; ++i) { oacc0[i] *= esc; oacc1[i] *= esc; }
      }

      // --- P = exp2(S - m); row sum via one shuffle
      float rsum = 0.f;
#pragma unroll
      for (int i = 0; i < 16; ++i) { s0[i] = __builtin_amdgcn_exp2f(s0[i] - mrun); rsum += s0[i]; }
#pragma unroll
      for (int i = 0; i < 16; ++i) { s1[i] = __builtin_amdgcn_exp2f(s1[i] - mrun); rsum += s1[i]; }
      rsum += __shfl_xor(rsum, 32);
      lrun += rsum;

      // --- build PV B-fragments in-register (cvt_pk + permlane32_swap)
      bf16x8 pf[4];
#pragma unroll
      for (int ks = 0; ks < 4; ++ks) {
        const int base = (ks & 1) * 8;
        unsigned ca, cb, cc, cd;
        if (ks < 2) {
          ca = cvtpk_bf16(s0[base + 0], s0[base + 1]);
          cb = cvtpk_bf16(s0[base + 2], s0[base + 3]);
          cc = cvtpk_bf16(s0[base + 4], s0[base + 5]);
          cd = cvtpk_bf16(s0[base + 6], s0[base + 7]);
        } else {
          ca = cvtpk_bf16(s1[base + 0], s1[base + 1]);
          cb = cvtpk_bf16(s1[base + 2], s1[base + 3]);
          cc = cvtpk_bf16(s1[base + 4], s1[base + 5]);
          cd = cvtpk_bf16(s1[base + 6], s1[base + 7]);
        }
        // vdst.row1 <-> vsrc.row0 (verified R14)
        asm volatile("v_permlane32_swap_b32 %0, %1" : "+v"(ca), "+v"(cc));
        asm volatile("v_permlane32_swap_b32 %0, %1" : "+v"(cb), "+v"(cd));
        union { unsigned u[4]; bf16x8 v; } pw;
        pw.u[0] = ca; pw.u[1] = cb; pw.u[2] = cc; pw.u[3] = cd;
        pf[ks] = pw.v;
      }

      // --- PV: oacc^T[dk][q] += V^T frag x P^T frag
      __builtin_amdgcn_s_setprio(1);
#pragma unroll
      for (int ks = 0; ks < 4; ++ks) {
        int key2b = (ks * 16 + h5 * 8) * 2;
        {
          int row = q32;
          bf16x8 vf = *(const bf16x8*)((char*)Vt[p] + row * 128 + (key2b ^ ((row & 7) << 4)));
          oacc0 = __builtin_amdgcn_mfma_f32_32x32x16_bf16(vf, pf[ks], oacc0, 0, 0, 0);
        }
        {
          int row = 32 + q32;
          bf16x8 vf = *(const bf16x8*)((char*)Vt[p] + row * 128 + (key2b ^ ((row & 7) << 4)));
          oacc1 = __builtin_amdgcn_mfma_f32_32x32x16_bf16(vf, pf[ks], oacc1, 0, 0, 0);
        }
      }
      __builtin_amdgcn_s_setprio(0);
    }  // kt

    // epilogue
    float linv = 1.0f / lrun;
    bf16_t* optr = attn + ((size_t)b * NS + qrow_g) * ND + h * 64;
#pragma unroll
    for (int rr = 0; rr < 4; ++rr) {
      bf16x4 o4a, o4b;
#pragma unroll
      for (int j = 0; j < 4; ++j) {
        o4a[j] = (bf16_t)(oacc0[rr * 4 + j] * linv);
        o4b[j] = (bf16_t)(oacc1[rr * 4 + j] * linv);
      }
      *(bf16x4*)(optr + rr * 8 + h5 * 4) = o4a;
      *(bf16x4*)(optr + 32 + rr * 8 + h5 * 4) = o4b;
    }
  }  // ph
}

// ---------------- launch ----------------
extern "C" void kernel_launch(void* const* d_in, const int* in_sizes, int n_in,
                              void* d_out, int out_size, void* d_ws, size_t ws_size,
                              hipStream_t stream) {
  const float* q  = (const float*)d_in[0];
  const float* k  = (const float*)d_in[1];
  const float* v  = (const float*)d_in[2];
  // d_in[3] = mask (int32 tril, implemented analytically)
  const float* Wq = (const float*)d_in[4];
  const float* bq = (const float*)d_in[5];
  const float* Wk = (const float*)d_in[6];
  const float* bk = (const float*)d_in[7];
  const float* Wv = (const float*)d_in[8];
  const float* bv = (const float*)d_in[9];
  const float* Wo = (const float*)d_in[10];
  const float* bo = (const float*)d_in[11];
  float* out = (float*)d_out;

  const size_t NX = (size_t)NB * NS * ND;  // 8388608
  const size_t NW = (size_t)ND * ND;       // 1048576
  char* ws = (char*)d_ws;
  size_t off = 0;
  auto alloc = [&](size_t bytes) {
    char* p = ws + off;
    off += (bytes + 255) & ~(size_t)255;
    return p;
  };
  bf16_t* wqb = (bf16_t*)alloc(NW * 2);
  bf16_t* wkb = (bf16_t*)alloc(NW * 2);
  bf16_t* wvb = (bf16_t*)alloc(NW * 2);
  bf16_t* wob = (bf16_t*)alloc(NW * 2);
  bf16_t* q1  = (bf16_t*)alloc(NX * 2);
  bf16_t* k1  = (bf16_t*)alloc(NX * 2);
  bf16_t* v1t = (bf16_t*)alloc(NX * 2);   // transposed per-head: [bh][dk][s]
  bf16_t* at  = (bf16_t*)alloc(NX * 2);

  dim3 blk(256);
  cvt4_kernel<<<dim3(128, 4), blk, 0, stream>>>(Wq, wqb, Wk, wkb, Wv, wvb, Wo, wob, (long)NW);

  gemm_qkv<<<dim3(1536), dim3(256), 0, stream>>>(
      q, wqb, bq, q1, k, wkb, bk, k1, v, wvb, bv, v1t);

  attn_kernel<<<dim3(512), dim3(256), 0, stream>>>(q1, k1, v1t, at);

  gemm_bt<<<dim3(512), dim3(256), 0, stream>>>(at, wob, bo, out);
}